// Round 3
// baseline (7615.855 us; speedup 1.0000x reference)
//
#include <hip/hip_runtime.h>

#define B_SZ 2048
#define FEAT 840
#define HID  256
#define LAT  128
#define NQ   12
#define NEMB 512

#define T_SUB 60    // 14 tiles x 60 = 840 exactly; lanes 0..59 active
#define NTILE 14
#define HSTR  66    // h1 row stride (60+2 halo, +pad; 66%32=2 -> ~2-way banks)
#define H2STR 62    // h2 row stride; h2 aliased into h1s region
#define CHALF 128   // c2 half-size: h1s holds one half of channels at a time

// numpy pairwise 8-accumulator combine: ((r0+r1)+(r2+r3))+((r4+r5)+(r6+r7))
__device__ __forceinline__ float np8_combine(const float* r) {
    float sA = __fadd_rn(r[0], r[1]);
    float sB = __fadd_rn(r[2], r[3]);
    float sC = __fadd_rn(r[4], r[5]);
    float sD = __fadd_rn(r[6], r[7]);
    return __fadd_rn(__fadd_rn(sA, sB), __fadd_rn(sC, sD));
}

// ---------------- w2 repack: w2s[c2][l][k], contiguous 384 floats per c2 ----
// per-(c2, wave) slice = 48 consecutive floats, 64B-aligned -> s_load_dwordx16
__global__ __launch_bounds__(256) void w2r_kernel(const float* __restrict__ w2,
                                                  float* __restrict__ w2s)
{
    int p = blockIdx.x * 256 + threadIdx.x;          // [0, 256*384)
    if (p >= HID * 384) return;
    int c2 = p / 384, r = p - c2 * 384;
    int l = r / 3, k = r - l * 3;
    w2s[p] = w2[(size_t)l * 768 + c2 * 3 + k];       // w2[l][c2][k]
}

// ---------------- encoder, numpy-f32 bit-faithful ----------------
// 512 threads = 8 waves. Wave w owns output channels l = w*16 .. w*16+15.
// Lane = time position within the 60-wide tile (lanes 60..63 idle/garbage).
// Weights are wave-uniform -> SGPR (s_load); h from LDS (3 ds_read_b32/c2);
// FMA = v_fmac(acc, s_weight, v_h): ~48 FMA + ~5 other VALU per c2 per wave.
// acc[16][3] carried across the two c2-halves -> per-(l,t,k) fma chain runs
// c2 = 0..255 ascending, combine (k0+k1)+k2, identical to prior kernels
// -> bit-exact. (Round-1 lesson: NO min-waves launch-bounds arg.)
template <int USE_WR>
__global__ __launch_bounds__(512) void enc_kernel(
    const float* __restrict__ x,  const float* __restrict__ w1,
    const float* __restrict__ b1, const float* __restrict__ w2,
    const float* __restrict__ w2s,
    const float* __restrict__ b2, float* __restrict__ zout)
{
    __shared__ float xp[FEAT + 4];          // 3376 B
    __shared__ float h1s[CHALF * HSTR];     // 33792 B; h2 tile aliased here
    __shared__ float leafs[LAT * 8];        // 4096 B   => ~41.3 KB total

    const int tid  = threadIdx.x;
    const int b    = blockIdx.x;
    const int lane = tid & 63;                                   // time pos
    const int wid  = __builtin_amdgcn_readfirstlane(tid >> 6);   // wave id

    // phase-A mapping: channel-in-half = tid>>2, local base = tid&3
    const int ac = tid >> 2;
    const int lb = tid & 3;

    // conv1 weights for this thread's channel, both halves
    float w1v[2][3], b1v[2];
#pragma unroll
    for (int hf = 0; hf < 2; ++hf) {
        int c = hf * CHALF + ac;
        w1v[hf][0] = w1[c*3 + 0];
        w1v[hf][1] = w1[c*3 + 1];
        w1v[hf][2] = w1[c*3 + 2];
        b1v[hf]    = b1[c];
    }

    // b2 for this wave's 16 output channels (uniform -> scalar regs)
    float b2v[16];
#pragma unroll
    for (int j = 0; j < 16; ++j) b2v[j] = b2[wid*16 + j];

    for (int i = tid; i < FEAT + 2; i += 512)
        xp[i] = (i >= 1 && i <= FEAT) ? x[(size_t)b*FEAT + i - 1] : 0.f;

    // numpy pairwise-840 leaf state (threads 0..127, one l each)
    float racc[8];
    int leaf_id = 0, leaf_pos = 0;
#pragma unroll
    for (int j = 0; j < 8; ++j) racc[j] = 0.f;

    __syncthreads();
    for (int t0 = 0; t0 < FEAT; t0 += T_SUB) {
        float acc[16][3];
#pragma unroll
        for (int l = 0; l < 16; ++l)
#pragma unroll
            for (int k = 0; k < 3; ++k) acc[l][k] = 0.f;

#pragma unroll
        for (int hf = 0; hf < 2; ++hf) {
            // ---- phase A (half hf): h1[ac][local], local = 0..61 (halo) ----
            {
                const float wA = w1v[hf][0], wB = w1v[hf][1], wC = w1v[hf][2];
                const float bb = b1v[hf];
#pragma unroll
                for (int i = 0; i < 16; ++i) {
                    int local = lb + 4*i;
                    if (local < T_SUB + 2) {
                        int tg = t0 - 1 + local;
                        float v = 0.f;
                        if (tg >= 0 && tg < FEAT) {
                            float s = __fadd_rn(__fadd_rn(__fmul_rn(wA, xp[tg]),
                                                          __fmul_rn(wB, xp[tg+1])),
                                                __fmul_rn(wC, xp[tg+2]));
                            s = __fadd_rn(s, bb);
                            v = s > 0.f ? s : 0.f;
                        }
                        h1s[ac*HSTR + local] = v;
                    }
                }
            }
            __syncthreads();

            // ---- phase B (half hf): c2 = hf*128 + cc ascending ----
            {
                const float* __restrict__ hp = &h1s[lane];
                if (USE_WR) {
                    const float* __restrict__ wv0 =
                        w2s + (size_t)(hf*CHALF)*384 + wid*48;
#pragma unroll 1
                    for (int cc = 0; cc < CHALF; ++cc) {
                        const float* __restrict__ wv = wv0 + (size_t)cc*384;
                        const float* __restrict__ hq = hp + cc*HSTR;
                        float H0 = hq[0], H1 = hq[1], H2 = hq[2];
#pragma unroll
                        for (int l = 0; l < 16; ++l) {
                            acc[l][0] = __fmaf_rn(wv[l*3+0], H0, acc[l][0]);
                            acc[l][1] = __fmaf_rn(wv[l*3+1], H1, acc[l][1]);
                            acc[l][2] = __fmaf_rn(wv[l*3+2], H2, acc[l][2]);
                        }
                    }
                } else {
                    const float* __restrict__ wb =
                        w2 + (size_t)(wid*16)*768 + (size_t)(hf*CHALF)*3;
#pragma unroll 1
                    for (int cc = 0; cc < CHALF; ++cc) {
                        const float* __restrict__ wv = wb + cc*3;
                        const float* __restrict__ hq = hp + cc*HSTR;
                        float H0 = hq[0], H1 = hq[1], H2 = hq[2];
#pragma unroll
                        for (int l = 0; l < 16; ++l) {
                            acc[l][0] = __fmaf_rn(wv[l*768+0], H0, acc[l][0]);
                            acc[l][1] = __fmaf_rn(wv[l*768+1], H1, acc[l][1]);
                            acc[l][2] = __fmaf_rn(wv[l*768+2], H2, acc[l][2]);
                        }
                    }
                }
            }
            __syncthreads();   // h1s reads done before next half / h2 overwrite
        }

        // h2 = fl(fl(k0+k1)+k2) + b2, relu -> aliased LDS (h1s region)
        if (lane < T_SUB) {
#pragma unroll
            for (int l = 0; l < 16; ++l) {
                float hh = __fadd_rn(__fadd_rn(acc[l][0], acc[l][1]), acc[l][2]);
                hh = __fadd_rn(hh, b2v[l]);
                hh = hh > 0.f ? hh : 0.f;
                h1s[(wid*16 + l)*H2STR + lane] = hh;
            }
        }
        __syncthreads();

        // reducer: threads 0..127 ingest T_SUB t's in order into numpy leaves
        if (tid < LAT) {
            for (int tt = 0; tt < T_SUB; ++tt) {
                float v = h1s[tid*H2STR + tt];
                int j = leaf_pos & 7;
                racc[j] = (leaf_pos < 8) ? v : __fadd_rn(racc[j], v);
                ++leaf_pos;
                int llen = (leaf_id == 7) ? 112 : 104;
                if (leaf_pos == llen) {
                    leafs[tid*8 + leaf_id] = np8_combine(racc);
                    ++leaf_id; leaf_pos = 0;
                }
            }
        }
        __syncthreads();   // reducer done before next tile's phase A writes h1s
    }

    // numpy pairwise-840 recombination
    if (tid < LAT) {
        const float* L = &leafs[tid*8];
        float s0 = __fadd_rn(L[0], L[1]);
        float s1 = __fadd_rn(L[2], L[3]);
        float sA = __fadd_rn(s0, s1);
        float s2 = __fadd_rn(L[4], L[5]);
        float s3 = __fadd_rn(L[6], L[7]);
        float sB = __fadd_rn(s2, s3);
        float tot = __fadd_rn(sA, sB);
        zout[(size_t)b*LAT + tid] = __fdiv_rn(tot, 840.0f);
    }
}

// ---------------- RVQ, numpy-f32 bit-faithful ----------------
__global__ __launch_bounds__(256) void rvq32_kernel(
    const float* __restrict__ cb, const float* __restrict__ z,
    float* __restrict__ zqout, float* __restrict__ oidx)
{
    __shared__ float rr[LAT];
    __shared__ float Ash;
    __shared__ float redd[256];
    __shared__ int   rede[256];
    __shared__ float sredd[64];
    __shared__ int   srede[64];
    __shared__ int   beste;
    __shared__ float qv[NQ * LAT];

    const int tid = threadIdx.x;
    const int b   = blockIdx.x;

    if (tid < LAT) rr[tid] = z[(size_t)b*LAT + tid];
    __syncthreads();

    for (int q = 0; q < NQ; ++q) {
        const float* __restrict__ cbq = cb + (size_t)q * NEMB * LAT;

        if (tid == 0) {
            float r8[8];
#pragma unroll
            for (int j = 0; j < 8; ++j) r8[j] = __fmul_rn(rr[j], rr[j]);
            for (int i = 8; i < LAT; i += 8)
#pragma unroll
                for (int j = 0; j < 8; ++j)
                    r8[j] = __fadd_rn(r8[j], __fmul_rn(rr[i+j], rr[i+j]));
            Ash = np8_combine(r8);
        }
        __syncthreads();

        float dmin = 0.f; int emin = 0;
#pragma unroll
        for (int h = 0; h < 2; ++h) {
            int e = 2*tid + h;
            const float* __restrict__ cp = cbq + (size_t)e*LAT;
            float dot = 0.f;
            float c8[8];
#pragma unroll
            for (int j = 0; j < 8; ++j) {
                float c = cp[j];
                c8[j] = __fmul_rn(c, c);
                dot = __fmaf_rn(c, rr[j], dot);
            }
            for (int i = 8; i < LAT; i += 8)
#pragma unroll
                for (int j = 0; j < 8; ++j) {
                    float c = cp[i+j];
                    dot = __fmaf_rn(c, rr[i+j], dot);
                    c8[j] = __fadd_rn(c8[j], __fmul_rn(c, c));
                }
            float cn = np8_combine(c8);
            float G  = __fmul_rn(2.0f, dot);
            float d  = __fadd_rn(__fsub_rn(Ash, G), cn);
            if (h == 0) { dmin = d; emin = e; }
            else if (d < dmin) { dmin = d; emin = e; }
        }
        redd[tid] = dmin; rede[tid] = emin;
        __syncthreads();

        if (tid < 64) {
            float bb = redd[tid*4]; int ee = rede[tid*4];
            for (int j = 1; j < 4; ++j) {
                float dj = redd[tid*4 + j];
                if (dj < bb) { bb = dj; ee = rede[tid*4 + j]; }
            }
            sredd[tid] = bb; srede[tid] = ee;
        }
        __syncthreads();
        if (tid == 0) {
            float bb = sredd[0]; int ee = srede[0];
            for (int j = 1; j < 64; ++j) {
                float dj = sredd[j];
                if (dj < bb) { bb = dj; ee = srede[j]; }
            }
            beste = ee;
            oidx[(size_t)b*NQ + q] = (float)ee;
        }
        __syncthreads();

        if (tid < LAT) {
            float cv = cbq[(size_t)beste*LAT + tid];
            qv[q*LAT + tid] = cv;
            rr[tid] = __fsub_rn(rr[tid], cv);
        }
        __syncthreads();
    }

    if (tid < LAT) {
        float s = qv[tid];
        for (int s2 = 1; s2 < NQ; ++s2)
            s = __fadd_rn(s, qv[s2*LAT + tid]);
        zqout[(size_t)b*LAT + tid] = s;
    }
}

extern "C" void kernel_launch(void* const* d_in, const int* in_sizes, int n_in,
                              void* d_out, int out_size, void* d_ws, size_t ws_size,
                              hipStream_t stream)
{
    (void)in_sizes; (void)n_in; (void)out_size;
    const float* x  = (const float*)d_in[0];
    const float* w1 = (const float*)d_in[1];
    const float* b1 = (const float*)d_in[2];
    const float* w2 = (const float*)d_in[3];
    const float* b2 = (const float*)d_in[4];
    const float* cb = (const float*)d_in[5];

    float* out  = (float*)d_out;
    float* zq   = out;                         // 2048*1*128 floats
    float* oidx = out + (size_t)B_SZ * LAT;    // 2048*1*12 floats

    const size_t w2s_bytes = (size_t)HID * 384 * sizeof(float);  // 393216

    if (ws_size >= w2s_bytes) {
        float* w2s = (float*)d_ws;
        w2r_kernel<<<(HID*384 + 255)/256, 256, 0, stream>>>(w2, w2s);
        enc_kernel<1><<<B_SZ, 512, 0, stream>>>(x, w1, b1, w2, w2s, b2, zq);
    } else {
        enc_kernel<0><<<B_SZ, 512, 0, stream>>>(x, w1, b1, w2, nullptr, b2, zq);
    }
    rvq32_kernel<<<B_SZ, 256, 0, stream>>>(cb, zq, zq, oidx);
}